// Round 1
// baseline (1011.624 us; speedup 1.0000x reference)
//
#include <hip/hip_runtime.h>
#include <stdint.h>

// ---------------- problem constants ----------------
#define NWIN   4096
#define NTOK   49
#define DIMT   256
#define NH     8
#define HD     32
#define KQKV   768            // 3*DIM
#define MROWS  (NWIN * NTOK)  // 200704
#define SCALE_Q 0.17677669529663687f  // 32^-0.5

typedef __attribute__((ext_vector_type(8))) short short8;   // 8 bf16 = 4 VGPRs
typedef __attribute__((ext_vector_type(4))) float f32x4;

// bf16 helpers (RNE)
__device__ __forceinline__ unsigned short f2bf(float f) {
    unsigned int u = __builtin_bit_cast(unsigned int, f);
    u = u + 0x7fffu + ((u >> 16) & 1u);
    return (unsigned short)(u >> 16);
}
__device__ __forceinline__ float bf2f(unsigned short b) {
    unsigned int u = ((unsigned int)b) << 16;
    return __builtin_bit_cast(float, u);
}

// XOR swizzle: spread rows across banks; keeps 16B alignment (flips byte bits 4..6)
#define SWZ(byteoff, row) ((byteoff) ^ (((row) & 7) << 4))

// ---------------- prep: weights -> bf16 transposed, bias table ----------------
__global__ void prep_kernel(const float* __restrict__ qkv_w,   // [256][768]
                            const float* __restrict__ proj_w,  // [256][256]
                            const float* __restrict__ tbl,     // [169][8]
                            unsigned short* __restrict__ wTq,  // [768][256] bf16
                            unsigned short* __restrict__ wTp,  // [256][256] bf16
                            float* __restrict__ biasF)         // [8][49][49]
{
    int i = blockIdx.x * 256 + threadIdx.x;   // grid covers 768*256
    if (i < 768 * 256) {
        int n = i >> 8, k = i & 255;
        float v = qkv_w[k * 768 + n];
        if (n % 3 == 0) v *= SCALE_Q;         // fold q-scale into weights
        wTq[i] = f2bf(v);
    }
    if (i < 256 * 256) {
        int n = i >> 8, k = i & 255;
        wTp[i] = f2bf(proj_w[k * 256 + n]);
    }
    if (i < NH * NTOK * NTOK) {
        int h = i / (NTOK * NTOK), r = i % (NTOK * NTOK);
        int q = r / NTOK, kk = r % NTOK;
        int dy = q / 7 - kk / 7 + 6;
        int dx = q % 7 - kk % 7 + 6;
        biasF[i] = tbl[(dy * 13 + dx) * NH + h];
    }
}

// ---------------- convert x fp32 -> bf16 ----------------
__global__ void convert_x_kernel(const float4* __restrict__ x,
                                 unsigned short* __restrict__ xb, int n4)
{
    int i = blockIdx.x * blockDim.x + threadIdx.x;
    int stride = gridDim.x * blockDim.x;
    for (; i < n4; i += stride) {
        float4 v = x[i];
        uint2 o;
        o.x = (unsigned int)f2bf(v.x) | ((unsigned int)f2bf(v.y) << 16);
        o.y = (unsigned int)f2bf(v.z) | ((unsigned int)f2bf(v.w) << 16);
        *(uint2*)(xb + (size_t)i * 4) = o;
    }
}

// ---------------- GEMM: C[M,N] = A[M,K](bf16) @ Bt[N,K](bf16)^T + bias ----------------
// EPI==0: qkv epilogue (scale q-cols of bias, store bf16)
// EPI==1: proj epilogue (store fp32)
template <int EPI>
__global__ __launch_bounds__(256) void gemm_kernel(
    const unsigned short* __restrict__ A,   // [M][K] bf16
    const unsigned short* __restrict__ Bt,  // [N][K] bf16
    const float* __restrict__ bias,         // [N] fp32
    void* __restrict__ out, int M, int N, int K)
{
    __shared__ unsigned short Al[128 * 64];
    __shared__ unsigned short Bl[128 * 64];
    const int tid  = threadIdx.x;
    const int lane = tid & 63, w = tid >> 6;
    const int wr = w >> 1, wc = w & 1;
    const int l15 = lane & 15, g = lane >> 4;
    const int bn = blockIdx.x, bm = blockIdx.y;   // bn in x => row-panel L2 reuse

    f32x4 acc[4][4];
    for (int i = 0; i < 4; ++i)
        for (int j = 0; j < 4; ++j) acc[i][j] = (f32x4){0.f, 0.f, 0.f, 0.f};

    const int nkt = K >> 6;
    for (int kt = 0; kt < nkt; ++kt) {
        __syncthreads();
        // stage A and Bt tiles: 128 rows x 64 k (bf16), 16B chunks, swizzled
        for (int i = 0; i < 4; ++i) {
            int c = tid + i * 256;            // 0..1023
            int row = c >> 3, k8 = c & 7;
            uint4 va = *(const uint4*)(A  + (size_t)(bm * 128 + row) * K + kt * 64 + k8 * 8);
            uint4 vb = *(const uint4*)(Bt + (size_t)(bn * 128 + row) * K + kt * 64 + k8 * 8);
            int boff = SWZ(row * 128 + k8 * 16, row);
            *(uint4*)((char*)Al + boff) = va;
            *(uint4*)((char*)Bl + boff) = vb;
        }
        __syncthreads();
        for (int kk = 0; kk < 2; ++kk) {
            short8 af[4], bf[4];
            for (int mi = 0; mi < 4; ++mi) {
                int r = wr * 64 + mi * 16 + l15;
                af[mi] = *(const short8*)((const char*)Al + SWZ(r * 128 + kk * 64 + g * 16, r));
            }
            for (int ni = 0; ni < 4; ++ni) {
                int r = wc * 64 + ni * 16 + l15;
                bf[ni] = *(const short8*)((const char*)Bl + SWZ(r * 128 + kk * 64 + g * 16, r));
            }
            for (int mi = 0; mi < 4; ++mi)
                for (int ni = 0; ni < 4; ++ni)
                    acc[mi][ni] = __builtin_amdgcn_mfma_f32_16x16x32_bf16(
                        af[mi], bf[ni], acc[mi][ni], 0, 0, 0);
        }
    }
    // epilogue: C layout col=lane&15, row=(lane>>4)*4+reg  [m89 verified]
    for (int mi = 0; mi < 4; ++mi)
        for (int ni = 0; ni < 4; ++ni) {
            int colg = bn * 128 + wc * 64 + ni * 16 + l15;
            float bv = bias[colg];
            if (EPI == 0) { if (colg % 3 == 0) bv *= SCALE_Q; }
            for (int r = 0; r < 4; ++r) {
                int rowg = bm * 128 + wr * 64 + mi * 16 + g * 4 + r;
                float v = acc[mi][ni][r] + bv;
                if (EPI == 0)
                    ((unsigned short*)out)[(size_t)rowg * N + colg] = f2bf(v);
                else
                    ((float*)out)[(size_t)rowg * N + colg] = v;
            }
        }
}

// ---------------- fused window attention ----------------
// grid: (4 head-pairs, 4096 windows), 256 threads = 4 waves.
// wave w: head_local = w>>1, row_half = w&1 (rows [rh*32, rh*32+32))
__global__ __launch_bounds__(256) void attn_kernel(
    const unsigned short* __restrict__ qkv,   // [M][768] bf16
    const int* __restrict__ mask,             // [B][49*49]
    const float* __restrict__ biasF,          // [8][49][49]
    unsigned short* __restrict__ outA)        // [M][256] bf16
{
    __shared__ unsigned short slab[64 * 192];  // 2 heads x (q,k,v interleaved), 64 padded rows
    __shared__ unsigned short Pl[2][64 * 64];  // per-head P matrix (bf16)
    __shared__ float maskf[NTOK * NTOK];

    const int hp = blockIdx.x;       // head pair 0..3
    const int b  = blockIdx.y;       // window 0..4095
    const int tid = threadIdx.x;
    const int lane = tid & 63, w = tid >> 6;
    const int l15 = lane & 15, g = lane >> 4;

    // stage slab rows 0..48 (24 x 16B chunks per row), swizzled
    for (int c = tid; c < 49 * 24; c += 256) {
        int r = c / 24, c16 = c % 24;
        uint4 v = *(const uint4*)(qkv + (size_t)(b * NTOK + r) * KQKV + hp * 192 + c16 * 8);
        *(uint4*)((char*)slab + SWZ(r * 384 + c16 * 16, r)) = v;
    }
    // zero pad rows 49..63
    for (int c = tid; c < 15 * 24; c += 256) {
        int r = 49 + c / 24, c16 = c % 24;
        *(uint4*)((char*)slab + SWZ(r * 384 + c16 * 16, r)) = (uint4){0u, 0u, 0u, 0u};
    }
    // additive mask
    for (int i = tid; i < NTOK * NTOK; i += 256)
        maskf[i] = (1.0f - (float)mask[(size_t)b * (NTOK * NTOK) + i]) * -1e10f;
    __syncthreads();

    const int hl = w >> 1;            // local head in pair
    const int rh = w & 1;             // row half (q rows rh*32..rh*32+31)
    const int h  = hp * 2 + hl;       // global head

    // ---- K fragments (B-operand of QK^T): lane holds K[key=l15+nt*16][kd=g*8+j]
    short8 kf[4];
    for (int nt = 0; nt < 4; ++nt) {
        int key = nt * 16 + l15;
        short8 t;
        for (int j = 0; j < 8; ++j) {
            int kd = g * 8 + j;
            t[j] = (short)*(const unsigned short*)(
                (const char*)slab + SWZ(key * 384 + (hl * 96 + 3 * kd + 1) * 2, key));
        }
        kf[nt] = t;
    }

    // ---- QK^T: S[q][key], q rows of this wave's half
    f32x4 s[2][4];
    for (int mi = 0; mi < 2; ++mi) {
        int mt = rh * 2 + mi;
        int q = mt * 16 + l15;
        short8 qf;
        for (int j = 0; j < 8; ++j) {
            int kd = g * 8 + j;
            qf[j] = (short)*(const unsigned short*)(
                (const char*)slab + SWZ(q * 384 + (hl * 96 + 3 * kd + 0) * 2, q));
        }
        for (int nt = 0; nt < 4; ++nt)
            s[mi][nt] = __builtin_amdgcn_mfma_f32_16x16x32_bf16(
                qf, kf[nt], (f32x4){0.f, 0.f, 0.f, 0.f}, 0, 0, 0);
    }

    // ---- bias + mask + softmax (row q = mt*16 + g*4 + reg), write normalized P
    for (int mi = 0; mi < 2; ++mi) {
        int mt = rh * 2 + mi;
        for (int r = 0; r < 4; ++r) {
            int q = mt * 16 + g * 4 + r;
            float vals[4];
            for (int nt = 0; nt < 4; ++nt) {
                int key = nt * 16 + l15;
                float v;
                if (q < NTOK && key < NTOK)
                    v = s[mi][nt][r] + biasF[(h * NTOK + q) * NTOK + key] + maskf[q * NTOK + key];
                else
                    v = -1e30f;
                vals[nt] = v;
            }
            float m = fmaxf(fmaxf(vals[0], vals[1]), fmaxf(vals[2], vals[3]));
            for (int x = 1; x < 16; x <<= 1) m = fmaxf(m, __shfl_xor(m, x, 64));
            float sum = 0.f;
            for (int nt = 0; nt < 4; ++nt) { vals[nt] = __expf(vals[nt] - m); sum += vals[nt]; }
            for (int x = 1; x < 16; x <<= 1) sum += __shfl_xor(sum, x, 64);
            float rs = 1.0f / sum;
            for (int nt = 0; nt < 4; ++nt) {
                int key = nt * 16 + l15;
                *(unsigned short*)((char*)&Pl[hl][0] + SWZ(q * 128 + key * 2, q)) =
                    f2bf(vals[nt] * rs);
            }
        }
    }
    // NOTE: Pl[hl] rows [rh*32, rh*32+32) written and read by this wave only -> no barrier.

    // ---- V fragments: lane holds V[key=kt*32+g*8+j][d=nt*16+l15]
    short8 vf[2][2];
    for (int kt = 0; kt < 2; ++kt)
        for (int nt = 0; nt < 2; ++nt) {
            int d = nt * 16 + l15;
            short8 t;
            for (int j = 0; j < 8; ++j) {
                int key = kt * 32 + g * 8 + j;
                t[j] = (short)*(const unsigned short*)(
                    (const char*)slab + SWZ(key * 384 + (hl * 96 + 3 * d + 2) * 2, key));
            }
            vf[kt][nt] = t;
        }

    // ---- PV
    f32x4 o[2][2];
    for (int mi = 0; mi < 2; ++mi)
        for (int nt = 0; nt < 2; ++nt) o[mi][nt] = (f32x4){0.f, 0.f, 0.f, 0.f};
    for (int mi = 0; mi < 2; ++mi) {
        int mt = rh * 2 + mi;
        int q = mt * 16 + l15;
        for (int kt = 0; kt < 2; ++kt) {
            short8 pf = *(const short8*)((const char*)&Pl[hl][0] + SWZ(q * 128 + kt * 64 + g * 16, q));
            for (int nt = 0; nt < 2; ++nt)
                o[mi][nt] = __builtin_amdgcn_mfma_f32_16x16x32_bf16(pf, vf[kt][nt], o[mi][nt], 0, 0, 0);
        }
    }

    // ---- store attn_out[b*49+q][h*32+d] bf16
    for (int mi = 0; mi < 2; ++mi) {
        int mt = rh * 2 + mi;
        for (int nt = 0; nt < 2; ++nt) {
            int d = nt * 16 + l15;
            for (int r = 0; r < 4; ++r) {
                int q = mt * 16 + g * 4 + r;
                if (q < NTOK)
                    outA[(size_t)(b * NTOK + q) * DIMT + h * HD + d] = f2bf(o[mi][nt][r]);
            }
        }
    }
}

// ---------------- launcher ----------------
extern "C" void kernel_launch(void* const* d_in, const int* in_sizes, int n_in,
                              void* d_out, int out_size, void* d_ws, size_t ws_size,
                              hipStream_t stream) {
    const float* x      = (const float*)d_in[0];
    const int*   mask   = (const int*)d_in[1];
    const float* qkv_w  = (const float*)d_in[2];
    const float* qkv_b  = (const float*)d_in[3];
    const float* proj_w = (const float*)d_in[4];
    const float* proj_b = (const float*)d_in[5];
    const float* tbl    = (const float*)d_in[6];

    char* ws = (char*)d_ws;
    // workspace layout (bytes):
    unsigned short* wTq   = (unsigned short*)(ws);                 // 393,216
    unsigned short* wTp   = (unsigned short*)(ws + 393216);        // 131,072
    float*          biasF = (float*)(ws + 524288);                 // 76,832
    unsigned short* xb    = (unsigned short*)(ws + 1048576);       // 102,760,448 (reused as attn_out)
    unsigned short* qkvb  = (unsigned short*)(ws + 1048576 + 102760448); // 308,281,344
    unsigned short* attnO = xb;  // alias: xb dead after GEMM1

    prep_kernel<<<dim3(768), dim3(256), 0, stream>>>(qkv_w, proj_w, tbl, wTq, wTp, biasF);
    convert_x_kernel<<<dim3(2048), dim3(256), 0, stream>>>(
        (const float4*)x, xb, (MROWS * DIMT) / 4);
    gemm_kernel<0><<<dim3(6, 1568), dim3(256), 0, stream>>>(
        xb, wTq, qkv_b, (void*)qkvb, MROWS, KQKV, DIMT);
    attn_kernel<<<dim3(4, NWIN), dim3(256), 0, stream>>>(qkvb, mask, biasF, attnO);
    gemm_kernel<1><<<dim3(2, 1568), dim3(256), 0, stream>>>(
        attnO, wTp, proj_b, d_out, MROWS, DIMT, DIMT);
}